// Round 6
// baseline (226.278 us; speedup 1.0000x reference)
//
#include <hip/hip_runtime.h>
#include <hip/hip_bf16.h>
#include <stdint.h>

#define B_ 2
#define N_ 2048
#define M_ 2048
#define C_ 1024
#define H_ 16
#define D_ 64

typedef __attribute__((ext_vector_type(8))) short s16x8;
typedef __attribute__((ext_vector_type(4))) short s16x4;
typedef __attribute__((ext_vector_type(4))) float f32x4;
typedef __attribute__((ext_vector_type(16))) float f32x16;

__device__ __attribute__((always_inline)) inline short f2b(float f){
    __hip_bfloat16 h = __float2bfloat16(f); short s; __builtin_memcpy(&s, &h, 2); return s;
}
__device__ __attribute__((always_inline)) inline float b2f(short s){
    __hip_bfloat16 h; __builtin_memcpy(&h, &s, 2); return __bfloat162float(h);
}

#define MFMA16(a,b,c) __builtin_amdgcn_mfma_f32_16x16x32_bf16(a,b,c,0,0,0)
#define MFMA32(a,b,c) __builtin_amdgcn_mfma_f32_32x32x16_bf16(a,b,c,0,0,0)

__device__ __attribute__((always_inline)) inline void gl_lds16(const void* g, void* l){
    __builtin_amdgcn_global_load_lds((__attribute__((address_space(1))) void*)g,
                                     (__attribute__((address_space(3))) void*)l, 16, 0, 0);
}
__device__ __attribute__((always_inline)) inline unsigned fbits(float f){
    unsigned u; __builtin_memcpy(&u, &f, 4); return u;
}

// ---------------- fused f32 -> bf16 convert: [query|key|Wq|Wk|Wv|Wo] -> ws[0..12M) ----
__global__ void cvt_all(const float* __restrict__ q, const float* __restrict__ k,
                        const float* __restrict__ wq, const float* __restrict__ wk,
                        const float* __restrict__ wv, const float* __restrict__ wo,
                        short* __restrict__ dst){
    long i = ((long)blockIdx.x * 256 + threadIdx.x) * 8;
    const float* src; long off;
    if      (i <  4194304L){ src = q;  off = i; }
    else if (i <  8388608L){ src = k;  off = i - 4194304L; }
    else if (i <  9437184L){ src = wq; off = i - 8388608L; }
    else if (i < 10485760L){ src = wk; off = i - 9437184L; }
    else if (i < 11534336L){ src = wv; off = i - 10485760L; }
    else                   { src = wo; off = i - 11534336L; }
    float4 a = *(const float4*)(src + off);
    float4 b = *(const float4*)(src + off + 4);
    s16x8 o;
    o[0]=f2b(a.x); o[1]=f2b(a.y); o[2]=f2b(a.z); o[3]=f2b(a.w);
    o[4]=f2b(b.x); o[5]=f2b(b.y); o[6]=f2b(b.z); o[7]=f2b(b.w);
    *(s16x8*)(dst + i) = o;
}

// ---------------- fused QKV projection GEMM ----------------
// A = qbf (n0<1024) or kbf; W = [Wq;Wk;Wv] (3072,1024) bf16 row-major.
// Epilogue: q -> +bq plain store; k -> plain store; v -> +bv stored transposed vT[b,h,d,m].
__global__ __launch_bounds__(256, 3) void gemm_qkv(
    const short* __restrict__ qbf, const short* __restrict__ kbf,
    const short* __restrict__ W,
    const float* __restrict__ bq, const float* __restrict__ bv,
    short* __restrict__ qproj, short* __restrict__ kproj, short* __restrict__ vT)
{
    __shared__ short As[128 * 32];
    __shared__ short Bs[128 * 32];
    const int n0 = blockIdx.x * 128, m0 = blockIdx.y * 128;
    const int sel = n0 >> 10;                 // 0=q, 1=k, 2=v (block-uniform)
    const short* A = (sel == 0) ? qbf : kbf;
    const int tid = threadIdx.x, lane = tid & 63, wave = tid >> 6;
    const int quad = lane >> 4, l16 = lane & 15;
    const int wr = (wave >> 1) * 64, wc = (wave & 1) * 64;
    const int srow = lane >> 2, scol = (lane & 3) * 8;

    f32x4 acc[4][4] = {};

    const short* Ag = A + (size_t)(m0 + wave * 32 + srow) * C_ + scol;
    const short* Bg = W + (size_t)(n0 + wave * 32 + srow) * C_ + scol;
    short* lA0 = As + (wave * 32) * 32;
    short* lA1 = As + (wave * 32 + 16) * 32;
    short* lB0 = Bs + (wave * 32) * 32;
    short* lB1 = Bs + (wave * 32 + 16) * 32;

    for (int k0 = 0; k0 < C_; k0 += 32){
        __syncthreads();
        gl_lds16(Ag + k0, lA0);
        gl_lds16(Ag + k0 + 16 * (size_t)C_, lA1);
        gl_lds16(Bg + k0, lB0);
        gl_lds16(Bg + k0 + 16 * (size_t)C_, lB1);
        __syncthreads();
        s16x8 af[4], bfr[4];
        #pragma unroll
        for (int t = 0; t < 4; t++) af[t]  = *(const s16x8*)&As[(wr + t*16 + l16) * 32 + quad * 8];
        #pragma unroll
        for (int t = 0; t < 4; t++) bfr[t] = *(const s16x8*)&Bs[(wc + t*16 + l16) * 32 + quad * 8];
        #pragma unroll
        for (int i = 0; i < 4; i++)
            #pragma unroll
            for (int j = 0; j < 4; j++)
                acc[i][j] = MFMA16(af[i], bfr[j], acc[i][j]);
    }

    // C/D layout (m89-verified): row(m) = quad*4 + r, col(n) = l16
    if (sel <= 1){
        short* dst = sel ? kproj : qproj;
        const float* bp = sel ? nullptr : bq;
        const int coff = sel << 10;
        #pragma unroll
        for (int j = 0; j < 4; j++){
            int c = n0 + wc + j * 16 + l16 - coff;
            float bb = bp ? bp[c] : 0.0f;
            #pragma unroll
            for (int i = 0; i < 4; i++){
                int row = m0 + wr + i * 16 + quad * 4;
                #pragma unroll
                for (int r = 0; r < 4; r++)
                    dst[(size_t)(row + r) * C_ + c] = f2b(acc[i][j][r] + bb);
            }
        }
    } else {
        // V: +bv, store transposed as vT[b,h,d,m] (round-2-proven uint2 scatter)
        #pragma unroll
        for (int j = 0; j < 4; j++){
            int col = n0 - 2048 + wc + j * 16 + l16;            // 0..1023
            int h = col >> 6, d = col & 63;
            float bb = bv[col];
            #pragma unroll
            for (int i = 0; i < 4; i++){
                int row = m0 + wr + i * 16 + quad * 4;
                int b = row >> 11, m = row & 2047;
                unsigned u0 = (unsigned)(unsigned short)f2b(acc[i][j][0] + bb) |
                              ((unsigned)(unsigned short)f2b(acc[i][j][1] + bb) << 16);
                unsigned u1 = (unsigned)(unsigned short)f2b(acc[i][j][2] + bb) |
                              ((unsigned)(unsigned short)f2b(acc[i][j][3] + bb) << 16);
                uint2 u; u.x = u0; u.y = u1;
                *(uint2*)&vT[(((size_t)(b * H_ + h)) * D_ + d) * M_ + m] = u;
            }
        }
    }
}

// ---------------- final projection + bias + residual (f32 out) ----------------
__global__ __launch_bounds__(256, 4) void gemm_out(
    const short* __restrict__ A, const short* __restrict__ W,
    const float* __restrict__ bias, const float* __restrict__ resid,
    float* __restrict__ outf)
{
    __shared__ short As[128 * 32];
    __shared__ short Bs[64 * 32];
    const int n0 = blockIdx.x * 64, m0 = blockIdx.y * 128;
    const int tid = threadIdx.x, lane = tid & 63, wave = tid >> 6;
    const int quad = lane >> 4, l16 = lane & 15;
    const int srow = lane >> 2, scol = (lane & 3) * 8;

    f32x4 acc[2][4] = {};
    const short* Ag = A + (size_t)(m0 + wave * 32 + srow) * C_ + scol;
    const short* Bg = W + (size_t)(n0 + wave * 16 + srow) * C_ + scol;
    short* lA0 = As + (wave * 32) * 32;
    short* lA1 = As + (wave * 32 + 16) * 32;
    short* lB  = Bs + (wave * 16) * 32;

    for (int k0 = 0; k0 < C_; k0 += 32){
        __syncthreads();
        gl_lds16(Ag + k0, lA0);
        gl_lds16(Ag + k0 + 16 * (size_t)C_, lA1);
        gl_lds16(Bg + k0, lB);
        __syncthreads();
        s16x8 af[2], bfr[4];
        #pragma unroll
        for (int t = 0; t < 2; t++) af[t]  = *(const s16x8*)&As[(wave*32 + t*16 + l16) * 32 + quad * 8];
        #pragma unroll
        for (int t = 0; t < 4; t++) bfr[t] = *(const s16x8*)&Bs[(t*16 + l16) * 32 + quad * 8];
        #pragma unroll
        for (int i = 0; i < 2; i++)
            #pragma unroll
            for (int j = 0; j < 4; j++)
                acc[i][j] = MFMA16(af[i], bfr[j], acc[i][j]);
    }

    #pragma unroll
    for (int j = 0; j < 4; j++){
        int c = n0 + j * 16 + l16;
        float bb = bias[c];
        #pragma unroll
        for (int i = 0; i < 2; i++){
            int row = m0 + wave * 32 + i * 16 + quad * 4;
            #pragma unroll
            for (int r = 0; r < 4; r++){
                size_t idx = (size_t)(row + r) * C_ + c;
                outf[idx] = acc[i][j][r] + bb + resid[idx];
            }
        }
    }
}

// ---------------- RoPE on K only (in place, bf16), native trig ----------------
__global__ void rope_k(short* __restrict__ k, const int* __restrict__ kpos){
    int t = blockIdx.x * blockDim.x + threadIdx.x;   // B*M*H*32 = 2M threads
    int i = t & 31;
    int h = (t >> 5) & (H_ - 1);
    int row = t >> 9;                                // b*M + m
    int pos = kpos[row];
    short* base = k + (size_t)row * C_ + h * D_;
    float x1 = b2f(base[i]), x2 = b2f(base[i + 32]);
    float invf = exp2f((float)i * (-13.287712379549449f / 32.0f));
    float f = (float)pos * invf;
    float c = __cosf(f), s = __sinf(f);
    base[i]      = f2b(x1 * c - x2 * s);
    base[i + 32] = f2b(x2 * c + x1 * s);
}

// ---------------- Flash attention (128-q blocks, 32x32x16 MFMA, S^T trick) ----------
// q-RoPE fused in prologue. P transform C-layout -> A-layout done IN REGISTER via
// lane^32 shuffles (no P LDS round-trip). Single barrier per stage (ping-pong +
// 2-deep register prefetch). LDS 35 KB -> 3 blocks/CU.
__global__ __launch_bounds__(256, 3) void flash_attn(
    const short* __restrict__ q, const short* __restrict__ k,
    const short* __restrict__ vt, short* __restrict__ o,
    const int* __restrict__ qpos)
{
    // shorts: K[2] @0 (2*64*68=8704), V[2] @8704, Lsum @17408 (128 f32), Linv @17664
    __shared__ short smem[17920];
    const int b = blockIdx.y >> 4, h = blockIdx.y & 15;
    const int n0 = blockIdx.x * 128;
    const int tid = threadIdx.x, lane = tid & 63, wave = tid >> 6;
    const int hi = lane >> 5, l32 = lane & 31;
    const int wq = wave & 1, kq = wave >> 1;

    // Q fragments (B-operand: lane n = q row, k = d), with fused RoPE + scale*log2e
    s16x8 qf[2][4];
    const float fac = 0.18033688011112042f;   // 0.125 * log2(e)
    #pragma unroll
    for (int qt = 0; qt < 2; qt++){
        int qrow = n0 + wq * 64 + qt * 32 + l32;
        const short* qg = &q[((size_t)(b * N_ + qrow)) * C_ + h * D_];
        float pos = (float)qpos[b * N_ + qrow];
        s16x8 raw[4];
        #pragma unroll
        for (int c = 0; c < 4; c++) raw[c] = *(const s16x8*)&qg[c * 16 + hi * 8];
        #pragma unroll
        for (int c = 0; c < 2; c++){
            s16x8 olo, ohi8;
            #pragma unroll
            for (int j = 0; j < 8; j++){
                int irot = c * 16 + hi * 8 + j;
                float invf = exp2f((float)irot * (-13.287712379549449f / 32.0f));
                float ang = pos * invf;
                float cs = __cosf(ang), sn = __sinf(ang);
                float x1 = b2f(raw[c][j]), x2 = b2f(raw[c + 2][j]);
                olo[j]  = f2b((x1 * cs - x2 * sn) * fac);
                ohi8[j] = f2b((x2 * cs + x1 * sn) * fac);
            }
            qf[qt][c] = olo; qf[qt][c + 2] = ohi8;
        }
    }

    const short* kg = k  + (size_t)(b * M_) * C_ + h * D_;
    const short* vg = vt + ((size_t)(b * H_ + h)) * D_ * M_;
    const int srow0 = tid >> 3, sseg = (tid & 7) * 8;

    union V8 { s16x8 v; uint2 u[2]; };
    V8 kreg[2], vreg[2];

    // prologue: load stage 0, write buf0, load stage 1
    #pragma unroll
    for (int ii = 0; ii < 2; ii++){
        int row = srow0 + 32 * ii;
        kreg[ii].v = *(const s16x8*)&kg[(size_t)row * C_ + sseg];
        vreg[ii].v = *(const s16x8*)&vg[(size_t)row * M_ + sseg];
    }
    #pragma unroll
    for (int ii = 0; ii < 2; ii++){
        int row = srow0 + 32 * ii;
        short* kd = &smem[row * 68 + sseg];
        *(uint2*)kd = kreg[ii].u[0]; *(uint2*)(kd + 4) = kreg[ii].u[1];
        short* vd = &smem[8704 + row * 68 + sseg];
        *(uint2*)vd = vreg[ii].u[0]; *(uint2*)(vd + 4) = vreg[ii].u[1];
    }
    #pragma unroll
    for (int ii = 0; ii < 2; ii++){
        int row = srow0 + 32 * ii;
        kreg[ii].v = *(const s16x8*)&kg[(size_t)(64 + row) * C_ + sseg];
        vreg[ii].v = *(const s16x8*)&vg[(size_t)row * M_ + 64 + sseg];
    }

    f32x16 zero16 = {};
    f32x16 oacc[2][2] = {zero16, zero16, zero16, zero16};
    float lacc[2] = {0.f, 0.f};

    for (int st = 0; st < 32; st++){
        const int p = st & 1, pn = p ^ 1;
        __syncthreads();     // buf p writes done; all waves finished reading buf pn
        if (st < 31){
            // write stage st+1 (held in regs) into buf pn
            #pragma unroll
            for (int ii = 0; ii < 2; ii++){
                int row = srow0 + 32 * ii;
                short* kd = &smem[pn * 4352 + row * 68 + sseg];
                *(uint2*)kd = kreg[ii].u[0]; *(uint2*)(kd + 4) = kreg[ii].u[1];
                short* vd = &smem[8704 + pn * 4352 + row * 68 + sseg];
                *(uint2*)vd = vreg[ii].u[0]; *(uint2*)(vd + 4) = vreg[ii].u[1];
            }
        }
        if (st < 30){
            // issue global loads for stage st+2
            #pragma unroll
            for (int ii = 0; ii < 2; ii++){
                int row = srow0 + 32 * ii;
                kreg[ii].v = *(const s16x8*)&kg[((size_t)((st + 2) * 64 + row)) * C_ + sseg];
                vreg[ii].v = *(const s16x8*)&vg[(size_t)row * M_ + (st + 2) * 64 + sseg];
            }
        }
        const short* Kp = &smem[p * 4352];
        const short* Vp = &smem[8704 + p * 4352];

        // K A-frags for this wave's 32-key strip
        s16x4 kf[4][2];
        #pragma unroll
        for (int c = 0; c < 4; c++){
            const short* a = &Kp[(kq * 32 + l32) * 68 + c * 16 + hi * 8];
            kf[c][0] = *(const s16x4*)a; kf[c][1] = *(const s16x4*)(a + 4);
        }

        s16x8 pf[2][2];
        #pragma unroll
        for (int qt = 0; qt < 2; qt++){
            f32x16 sv = {};
            #pragma unroll
            for (int c = 0; c < 4; c++){
                s16x8 ka = __builtin_shufflevector(kf[c][0], kf[c][1], 0,1,2,3,4,5,6,7);
                sv = MFMA32(ka, qf[qt][c], sv);
            }
            float ls = 0.f;
            unsigned pb[8];
            #pragma unroll
            for (int g = 0; g < 4; g++){
                float p0 = __builtin_amdgcn_exp2f(sv[4*g+0]);
                float p1 = __builtin_amdgcn_exp2f(sv[4*g+1]);
                float p2 = __builtin_amdgcn_exp2f(sv[4*g+2]);
                float p3 = __builtin_amdgcn_exp2f(sv[4*g+3]);
                ls += (p0 + p1) + (p2 + p3);
                pb[2*g]   = __builtin_amdgcn_perm(fbits(p1), fbits(p0), 0x07060302);
                pb[2*g+1] = __builtin_amdgcn_perm(fbits(p3), fbits(p2), 0x07060302);
            }
            lacc[qt] += ls;
            // C-layout -> A-operand layout via lane^32 exchange:
            // A-frag c: hi=0 needs {own pb[4c],pb[4c+1], partner pb[4c],pb[4c+1]}
            //           hi=1 needs {partner pb[4c+2],pb[4c+3], own pb[4c+2],pb[4c+3]}
            unsigned s0 = hi ? pb[0] : pb[2];
            unsigned s1 = hi ? pb[1] : pb[3];
            unsigned s2 = hi ? pb[4] : pb[6];
            unsigned s3 = hi ? pb[5] : pb[7];
            unsigned r0 = (unsigned)__shfl_xor((int)s0, 32);
            unsigned r1 = (unsigned)__shfl_xor((int)s1, 32);
            unsigned r2 = (unsigned)__shfl_xor((int)s2, 32);
            unsigned r3 = (unsigned)__shfl_xor((int)s3, 32);
            union { unsigned u[4]; s16x8 v; } f0, f1;
            f0.u[0] = hi ? r0 : pb[0];
            f0.u[1] = hi ? r1 : pb[1];
            f0.u[2] = hi ? pb[2] : r0;
            f0.u[3] = hi ? pb[3] : r1;
            f1.u[0] = hi ? r2 : pb[4];
            f1.u[1] = hi ? r3 : pb[5];
            f1.u[2] = hi ? pb[6] : r2;
            f1.u[3] = hi ? pb[7] : r3;
            pf[qt][0] = f0.v; pf[qt][1] = f1.v;
        }

        // PV: O[q][d] += P(64x32) . V(32x64)
        s16x8 vf[2][2];
        #pragma unroll
        for (int dt = 0; dt < 2; dt++)
            #pragma unroll
            for (int c = 0; c < 2; c++){
                const short* a = &Vp[(dt * 32 + l32) * 68 + kq * 32 + c * 16 + hi * 8];
                vf[dt][c] = __builtin_shufflevector(*(const s16x4*)a, *(const s16x4*)(a + 4),
                                                    0,1,2,3,4,5,6,7);
            }
        #pragma unroll
        for (int qt = 0; qt < 2; qt++)
            #pragma unroll
            for (int dt = 0; dt < 2; dt++)
                #pragma unroll
                for (int c = 0; c < 2; c++)
                    oacc[qt][dt] = MFMA32(pf[qt][c], vf[dt][c], oacc[qt][dt]);
    }

    __syncthreads();   // everyone done with K/V buffers

    float* LO   = (float*)smem;            // [128][65] f32 (overlays K/V bufs)
    float* Lsum = (float*)&smem[17408];    // 128 f32
    float* Linv = (float*)&smem[17664];    // 128 f32

    float l0[2];
    #pragma unroll
    for (int qt = 0; qt < 2; qt++)
        l0[qt] = lacc[qt] + __shfl_xor(lacc[qt], 32);

    if (kq == 1){
        #pragma unroll
        for (int qt = 0; qt < 2; qt++)
            Lsum[wq * 64 + qt * 32 + l32] = l0[qt];
        #pragma unroll
        for (int qt = 0; qt < 2; qt++)
            #pragma unroll
            for (int dt = 0; dt < 2; dt++)
                #pragma unroll
                for (int e = 0; e < 16; e++){
                    int qrow = wq * 64 + qt * 32 + (e & 3) + 8 * (e >> 2) + 4 * hi;
                    LO[qrow * 65 + dt * 32 + l32] = oacc[qt][dt][e];
                }
    }
    __syncthreads();
    if (kq == 0){
        #pragma unroll
        for (int qt = 0; qt < 2; qt++){
            float lt = l0[qt] + Lsum[wq * 64 + qt * 32 + l32];
            Linv[wq * 64 + qt * 32 + l32] = 1.0f / lt;
        }
        asm volatile("s_waitcnt lgkmcnt(0)" ::: "memory");
        #pragma unroll
        for (int qt = 0; qt < 2; qt++)
            #pragma unroll
            for (int dt = 0; dt < 2; dt++)
                #pragma unroll
                for (int e = 0; e < 16; e++){
                    int qrow = wq * 64 + qt * 32 + (e & 3) + 8 * (e >> 2) + 4 * hi;
                    float val = (oacc[qt][dt][e] + LO[qrow * 65 + dt * 32 + l32]) * Linv[qrow];
                    o[((size_t)(b * N_ + n0 + qrow)) * C_ + h * D_ + dt * 32 + l32] = f2b(val);
                }
    }
}

extern "C" void kernel_launch(void* const* d_in, const int* in_sizes, int n_in,
                              void* d_out, int out_size, void* d_ws, size_t ws_size,
                              hipStream_t stream) {
    const float* query = (const float*)d_in[0];
    const float* key   = (const float*)d_in[1];
    const int*   qpos  = (const int*)d_in[2];
    const int*   kpos  = (const int*)d_in[3];
    const float* Wq    = (const float*)d_in[4];
    const float* bq    = (const float*)d_in[5];
    const float* Wk    = (const float*)d_in[6];
    const float* Wv    = (const float*)d_in[7];
    const float* bv    = (const float*)d_in[8];
    const float* Wo    = (const float*)d_in[9];
    const float* bo    = (const float*)d_in[10];
    float* out = (float*)d_out;

    const size_t E4M = (size_t)4 * 1024 * 1024;
    const size_t E1M = (size_t)1024 * 1024;
    short* ws    = (short*)d_ws;
    short* qbf   = ws;                    // 4M (dead after proj -> reused as attn)
    short* kbf   = qbf   + E4M;           // 4M
    short* wqkvb = kbf   + E4M;           // 3M = [Wq;Wk;Wv]
    short* wob   = wqkvb + 3 * E1M;       // 1M
    short* qproj = wob   + E1M;           // 4M
    short* kproj = qproj + E4M;           // 4M
    short* vT    = kproj + E4M;           // 4M  -> total 24M shorts = 48 MB
    short* attn  = qbf;                   // alias

    // 1) fused converts (12M elements, contiguous dst)
    cvt_all<<<6144, 256, 0, stream>>>(query, key, Wq, Wk, Wv, Wo, ws);

    // 2) fused QKV projection; V stored transposed in epilogue
    gemm_qkv<<<dim3(24, 32), 256, 0, stream>>>(qbf, kbf, wqkvb, bq, bv,
                                               qproj, kproj, vT);

    // 3) RoPE on k only (q-RoPE fused into flash prologue)
    rope_k<<<(B_ * M_ * H_ * 32) / 256, 256, 0, stream>>>(kproj, kpos);

    // 4) flash attention -> attn [B,N,C] bf16
    flash_attn<<<dim3(16, 32), 256, 0, stream>>>(qproj, kproj, vT, attn, qpos);

    // 5) output projection + bias + residual -> f32 out
    gemm_out<<<dim3(16, 32), 256, 0, stream>>>(attn, wob, bo, query, out);
}

// Round 7
// 213.682 us; speedup vs baseline: 1.0589x; 1.0589x over previous
//
#include <hip/hip_runtime.h>
#include <hip/hip_bf16.h>
#include <stdint.h>

#define B_ 2
#define N_ 2048
#define M_ 2048
#define C_ 1024
#define H_ 16
#define D_ 64

typedef __attribute__((ext_vector_type(8))) short s16x8;
typedef __attribute__((ext_vector_type(4))) short s16x4;
typedef __attribute__((ext_vector_type(4))) float f32x4;
typedef __attribute__((ext_vector_type(16))) float f32x16;

__device__ __attribute__((always_inline)) inline short f2b(float f){
    __hip_bfloat16 h = __float2bfloat16(f); short s; __builtin_memcpy(&s, &h, 2); return s;
}
__device__ __attribute__((always_inline)) inline float b2f(short s){
    __hip_bfloat16 h; __builtin_memcpy(&h, &s, 2); return __bfloat162float(h);
}

#define MFMA16(a,b,c) __builtin_amdgcn_mfma_f32_16x16x32_bf16(a,b,c,0,0,0)
#define MFMA32(a,b,c) __builtin_amdgcn_mfma_f32_32x32x16_bf16(a,b,c,0,0,0)

__device__ __attribute__((always_inline)) inline void gl_lds16(const void* g, void* l){
    __builtin_amdgcn_global_load_lds((__attribute__((address_space(1))) void*)g,
                                     (__attribute__((address_space(3))) void*)l, 16, 0, 0);
}
__device__ __attribute__((always_inline)) inline unsigned fbits(float f){
    unsigned u; __builtin_memcpy(&u, &f, 4); return u;
}

// ---------------- fused f32 -> bf16 convert: [query|key|Wq|Wk|Wv|Wo] -> ws[0..12M) ----
__global__ void cvt_all(const float* __restrict__ q, const float* __restrict__ k,
                        const float* __restrict__ wq, const float* __restrict__ wk,
                        const float* __restrict__ wv, const float* __restrict__ wo,
                        short* __restrict__ dst){
    long i = ((long)blockIdx.x * 256 + threadIdx.x) * 8;
    const float* src; long off;
    if      (i <  4194304L){ src = q;  off = i; }
    else if (i <  8388608L){ src = k;  off = i - 4194304L; }
    else if (i <  9437184L){ src = wq; off = i - 8388608L; }
    else if (i < 10485760L){ src = wk; off = i - 9437184L; }
    else if (i < 11534336L){ src = wv; off = i - 10485760L; }
    else                   { src = wo; off = i - 11534336L; }
    float4 a = *(const float4*)(src + off);
    float4 b = *(const float4*)(src + off + 4);
    s16x8 o;
    o[0]=f2b(a.x); o[1]=f2b(a.y); o[2]=f2b(a.z); o[3]=f2b(a.w);
    o[4]=f2b(b.x); o[5]=f2b(b.y); o[6]=f2b(b.z); o[7]=f2b(b.w);
    *(s16x8*)(dst + i) = o;
}

// ---------------- fused QKV projection GEMM ----------------
__global__ __launch_bounds__(256, 3) void gemm_qkv(
    const short* __restrict__ qbf, const short* __restrict__ kbf,
    const short* __restrict__ W,
    const float* __restrict__ bq, const float* __restrict__ bv,
    short* __restrict__ qproj, short* __restrict__ kproj, short* __restrict__ vT)
{
    __shared__ short As[128 * 32];
    __shared__ short Bs[128 * 32];
    const int n0 = blockIdx.x * 128, m0 = blockIdx.y * 128;
    const int sel = n0 >> 10;                 // 0=q, 1=k, 2=v (block-uniform)
    const short* A = (sel == 0) ? qbf : kbf;
    const int tid = threadIdx.x, lane = tid & 63, wave = tid >> 6;
    const int quad = lane >> 4, l16 = lane & 15;
    const int wr = (wave >> 1) * 64, wc = (wave & 1) * 64;
    const int srow = lane >> 2, scol = (lane & 3) * 8;

    f32x4 acc[4][4] = {};

    const short* Ag = A + (size_t)(m0 + wave * 32 + srow) * C_ + scol;
    const short* Bg = W + (size_t)(n0 + wave * 32 + srow) * C_ + scol;
    short* lA0 = As + (wave * 32) * 32;
    short* lA1 = As + (wave * 32 + 16) * 32;
    short* lB0 = Bs + (wave * 32) * 32;
    short* lB1 = Bs + (wave * 32 + 16) * 32;

    for (int k0 = 0; k0 < C_; k0 += 32){
        __syncthreads();
        gl_lds16(Ag + k0, lA0);
        gl_lds16(Ag + k0 + 16 * (size_t)C_, lA1);
        gl_lds16(Bg + k0, lB0);
        gl_lds16(Bg + k0 + 16 * (size_t)C_, lB1);
        __syncthreads();
        s16x8 af[4], bfr[4];
        #pragma unroll
        for (int t = 0; t < 4; t++) af[t]  = *(const s16x8*)&As[(wr + t*16 + l16) * 32 + quad * 8];
        #pragma unroll
        for (int t = 0; t < 4; t++) bfr[t] = *(const s16x8*)&Bs[(wc + t*16 + l16) * 32 + quad * 8];
        #pragma unroll
        for (int i = 0; i < 4; i++)
            #pragma unroll
            for (int j = 0; j < 4; j++)
                acc[i][j] = MFMA16(af[i], bfr[j], acc[i][j]);
    }

    // C/D layout (m89-verified): row(m) = quad*4 + r, col(n) = l16
    if (sel <= 1){
        short* dst = sel ? kproj : qproj;
        const float* bp = sel ? nullptr : bq;
        const int coff = sel << 10;
        #pragma unroll
        for (int j = 0; j < 4; j++){
            int c = n0 + wc + j * 16 + l16 - coff;
            float bb = bp ? bp[c] : 0.0f;
            #pragma unroll
            for (int i = 0; i < 4; i++){
                int row = m0 + wr + i * 16 + quad * 4;
                #pragma unroll
                for (int r = 0; r < 4; r++)
                    dst[(size_t)(row + r) * C_ + c] = f2b(acc[i][j][r] + bb);
            }
        }
    } else {
        // V: +bv, store transposed as vT[b,h,d,m]
        #pragma unroll
        for (int j = 0; j < 4; j++){
            int col = n0 - 2048 + wc + j * 16 + l16;            // 0..1023
            int h = col >> 6, d = col & 63;
            float bb = bv[col];
            #pragma unroll
            for (int i = 0; i < 4; i++){
                int row = m0 + wr + i * 16 + quad * 4;
                int b = row >> 11, m = row & 2047;
                unsigned u0 = (unsigned)(unsigned short)f2b(acc[i][j][0] + bb) |
                              ((unsigned)(unsigned short)f2b(acc[i][j][1] + bb) << 16);
                unsigned u1 = (unsigned)(unsigned short)f2b(acc[i][j][2] + bb) |
                              ((unsigned)(unsigned short)f2b(acc[i][j][3] + bb) << 16);
                uint2 u; u.x = u0; u.y = u1;
                *(uint2*)&vT[(((size_t)(b * H_ + h)) * D_ + d) * M_ + m] = u;
            }
        }
    }
}

// ---------------- final projection + bias + residual (f32 out) ----------------
__global__ __launch_bounds__(256, 4) void gemm_out(
    const short* __restrict__ A, const short* __restrict__ W,
    const float* __restrict__ bias, const float* __restrict__ resid,
    float* __restrict__ outf)
{
    __shared__ short As[128 * 32];
    __shared__ short Bs[64 * 32];
    const int n0 = blockIdx.x * 64, m0 = blockIdx.y * 128;
    const int tid = threadIdx.x, lane = tid & 63, wave = tid >> 6;
    const int quad = lane >> 4, l16 = lane & 15;
    const int srow = lane >> 2, scol = (lane & 3) * 8;

    f32x4 acc[2][4] = {};
    const short* Ag = A + (size_t)(m0 + wave * 32 + srow) * C_ + scol;
    const short* Bg = W + (size_t)(n0 + wave * 16 + srow) * C_ + scol;
    short* lA0 = As + (wave * 32) * 32;
    short* lA1 = As + (wave * 32 + 16) * 32;
    short* lB  = Bs + (wave * 16) * 32;

    for (int k0 = 0; k0 < C_; k0 += 32){
        __syncthreads();
        gl_lds16(Ag + k0, lA0);
        gl_lds16(Ag + k0 + 16 * (size_t)C_, lA1);
        gl_lds16(Bg + k0, lB);
        __syncthreads();
        s16x8 af[2], bfr[4];
        #pragma unroll
        for (int t = 0; t < 2; t++) af[t]  = *(const s16x8*)&As[(wave*32 + t*16 + l16) * 32 + quad * 8];
        #pragma unroll
        for (int t = 0; t < 4; t++) bfr[t] = *(const s16x8*)&Bs[(t*16 + l16) * 32 + quad * 8];
        #pragma unroll
        for (int i = 0; i < 2; i++)
            #pragma unroll
            for (int j = 0; j < 4; j++)
                acc[i][j] = MFMA16(af[i], bfr[j], acc[i][j]);
    }

    #pragma unroll
    for (int j = 0; j < 4; j++){
        int c = n0 + j * 16 + l16;
        float bb = bias[c];
        #pragma unroll
        for (int i = 0; i < 2; i++){
            int row = m0 + wave * 32 + i * 16 + quad * 4;
            #pragma unroll
            for (int r = 0; r < 4; r++){
                size_t idx = (size_t)(row + r) * C_ + c;
                outf[idx] = acc[i][j][r] + bb + resid[idx];
            }
        }
    }
}

// ---------------- RoPE on K only (in place, bf16), native trig ----------------
__global__ void rope_k(short* __restrict__ k, const int* __restrict__ kpos){
    int t = blockIdx.x * blockDim.x + threadIdx.x;   // B*M*H*32 = 2M threads
    int i = t & 31;
    int h = (t >> 5) & (H_ - 1);
    int row = t >> 9;                                // b*M + m
    int pos = kpos[row];
    short* base = k + (size_t)row * C_ + h * D_;
    float x1 = b2f(base[i]), x2 = b2f(base[i + 32]);
    float invf = exp2f((float)i * (-13.287712379549449f / 32.0f));
    float f = (float)pos * invf;
    float c = __cosf(f), s = __sinf(f);
    base[i]      = f2b(x1 * c - x2 * s);
    base[i + 32] = f2b(x2 * c + x1 * s);
}

// ---------------- Flash attention (128-q blocks, 32x32x16 MFMA, S^T trick) ----------
// q-RoPE fused in prologue. P transform C-layout -> A-layout IN REGISTER via lane^32
// shuffles (no P LDS round-trip). Single barrier per stage, 2-deep prefetch.
// launch_bounds(256,2): ~150 VGPR + 64 AGPR fits under the 256 cap -> no spill
// (r6 at lb=3 spilled: VGPR capped ~170, WRITE_SIZE doubled).
__global__ __launch_bounds__(256, 2) void flash_attn(
    const short* __restrict__ q, const short* __restrict__ k,
    const short* __restrict__ vt, short* __restrict__ o,
    const int* __restrict__ qpos)
{
    // shorts: K[2] @0 (2*64*68=8704), V[2] @8704, Lsum @17408 (128 f32), Linv @17664
    __shared__ short smem[17920];
    const int b = blockIdx.y >> 4, h = blockIdx.y & 15;
    const int n0 = blockIdx.x * 128;
    const int tid = threadIdx.x, lane = tid & 63, wave = tid >> 6;
    const int hi = lane >> 5, l32 = lane & 31;
    const int wq = wave & 1, kq = wave >> 1;

    // Q fragments (B-operand: lane n = q row, k = d), with fused RoPE + scale*log2e
    s16x8 qf[2][4];
    const float fac = 0.18033688011112042f;   // 0.125 * log2(e)
    #pragma unroll
    for (int qt = 0; qt < 2; qt++){
        int qrow = n0 + wq * 64 + qt * 32 + l32;
        const short* qg = &q[((size_t)(b * N_ + qrow)) * C_ + h * D_];
        float pos = (float)qpos[b * N_ + qrow];
        s16x8 raw[4];
        #pragma unroll
        for (int c = 0; c < 4; c++) raw[c] = *(const s16x8*)&qg[c * 16 + hi * 8];
        #pragma unroll
        for (int c = 0; c < 2; c++){
            s16x8 olo, ohi8;
            #pragma unroll
            for (int j = 0; j < 8; j++){
                int irot = c * 16 + hi * 8 + j;
                float invf = exp2f((float)irot * (-13.287712379549449f / 32.0f));
                float ang = pos * invf;
                float cs = __cosf(ang), sn = __sinf(ang);
                float x1 = b2f(raw[c][j]), x2 = b2f(raw[c + 2][j]);
                olo[j]  = f2b((x1 * cs - x2 * sn) * fac);
                ohi8[j] = f2b((x2 * cs + x1 * sn) * fac);
            }
            qf[qt][c] = olo; qf[qt][c + 2] = ohi8;
        }
    }

    const short* kg = k  + (size_t)(b * M_) * C_ + h * D_;
    const short* vg = vt + ((size_t)(b * H_ + h)) * D_ * M_;
    const int srow0 = tid >> 3, sseg = (tid & 7) * 8;

    union V8 { s16x8 v; uint2 u[2]; };
    V8 kreg[2], vreg[2];

    // prologue: load stage 0, write buf0, load stage 1
    #pragma unroll
    for (int ii = 0; ii < 2; ii++){
        int row = srow0 + 32 * ii;
        kreg[ii].v = *(const s16x8*)&kg[(size_t)row * C_ + sseg];
        vreg[ii].v = *(const s16x8*)&vg[(size_t)row * M_ + sseg];
    }
    #pragma unroll
    for (int ii = 0; ii < 2; ii++){
        int row = srow0 + 32 * ii;
        short* kd = &smem[row * 68 + sseg];
        *(uint2*)kd = kreg[ii].u[0]; *(uint2*)(kd + 4) = kreg[ii].u[1];
        short* vd = &smem[8704 + row * 68 + sseg];
        *(uint2*)vd = vreg[ii].u[0]; *(uint2*)(vd + 4) = vreg[ii].u[1];
    }
    #pragma unroll
    for (int ii = 0; ii < 2; ii++){
        int row = srow0 + 32 * ii;
        kreg[ii].v = *(const s16x8*)&kg[(size_t)(64 + row) * C_ + sseg];
        vreg[ii].v = *(const s16x8*)&vg[(size_t)row * M_ + 64 + sseg];
    }

    f32x16 zero16 = {};
    f32x16 oacc[2][2] = {zero16, zero16, zero16, zero16};
    float lacc[2] = {0.f, 0.f};

    for (int st = 0; st < 32; st++){
        const int p = st & 1, pn = p ^ 1;
        __syncthreads();     // buf p writes done; all waves finished reading buf pn
        if (st < 31){
            // write stage st+1 (held in regs) into buf pn
            #pragma unroll
            for (int ii = 0; ii < 2; ii++){
                int row = srow0 + 32 * ii;
                short* kd = &smem[pn * 4352 + row * 68 + sseg];
                *(uint2*)kd = kreg[ii].u[0]; *(uint2*)(kd + 4) = kreg[ii].u[1];
                short* vd = &smem[8704 + pn * 4352 + row * 68 + sseg];
                *(uint2*)vd = vreg[ii].u[0]; *(uint2*)(vd + 4) = vreg[ii].u[1];
            }
        }
        if (st < 30){
            // issue global loads for stage st+2
            #pragma unroll
            for (int ii = 0; ii < 2; ii++){
                int row = srow0 + 32 * ii;
                kreg[ii].v = *(const s16x8*)&kg[((size_t)((st + 2) * 64 + row)) * C_ + sseg];
                vreg[ii].v = *(const s16x8*)&vg[(size_t)row * M_ + (st + 2) * 64 + sseg];
            }
        }
        const short* Kp = &smem[p * 4352];
        const short* Vp = &smem[8704 + p * 4352];

        // K A-frags for this wave's 32-key strip
        s16x4 kf[4][2];
        #pragma unroll
        for (int c = 0; c < 4; c++){
            const short* a = &Kp[(kq * 32 + l32) * 68 + c * 16 + hi * 8];
            kf[c][0] = *(const s16x4*)a; kf[c][1] = *(const s16x4*)(a + 4);
        }

        s16x8 pf[2][2];
        #pragma unroll
        for (int qt = 0; qt < 2; qt++){
            f32x16 sv = {};
            #pragma unroll
            for (int c = 0; c < 4; c++){
                s16x8 ka = __builtin_shufflevector(kf[c][0], kf[c][1], 0,1,2,3,4,5,6,7);
                sv = MFMA32(ka, qf[qt][c], sv);
            }
            float ls = 0.f;
            unsigned pb[8];
            #pragma unroll
            for (int g = 0; g < 4; g++){
                float p0 = __builtin_amdgcn_exp2f(sv[4*g+0]);
                float p1 = __builtin_amdgcn_exp2f(sv[4*g+1]);
                float p2 = __builtin_amdgcn_exp2f(sv[4*g+2]);
                float p3 = __builtin_amdgcn_exp2f(sv[4*g+3]);
                ls += (p0 + p1) + (p2 + p3);
                pb[2*g]   = __builtin_amdgcn_perm(fbits(p1), fbits(p0), 0x07060302);
                pb[2*g+1] = __builtin_amdgcn_perm(fbits(p3), fbits(p2), 0x07060302);
            }
            lacc[qt] += ls;
            // C-layout -> A-operand layout via lane^32 exchange
            unsigned s0 = hi ? pb[0] : pb[2];
            unsigned s1 = hi ? pb[1] : pb[3];
            unsigned s2 = hi ? pb[4] : pb[6];
            unsigned s3 = hi ? pb[5] : pb[7];
            unsigned r0 = (unsigned)__shfl_xor((int)s0, 32);
            unsigned r1 = (unsigned)__shfl_xor((int)s1, 32);
            unsigned r2 = (unsigned)__shfl_xor((int)s2, 32);
            unsigned r3 = (unsigned)__shfl_xor((int)s3, 32);
            union { unsigned u[4]; s16x8 v; } f0, f1;
            f0.u[0] = hi ? r0 : pb[0];
            f0.u[1] = hi ? r1 : pb[1];
            f0.u[2] = hi ? pb[2] : r0;
            f0.u[3] = hi ? pb[3] : r1;
            f1.u[0] = hi ? r2 : pb[4];
            f1.u[1] = hi ? r3 : pb[5];
            f1.u[2] = hi ? pb[6] : r2;
            f1.u[3] = hi ? pb[7] : r3;
            pf[qt][0] = f0.v; pf[qt][1] = f1.v;
        }

        // PV: O[q][d] += P(64x32) . V(32x64)
        s16x8 vf[2][2];
        #pragma unroll
        for (int dt = 0; dt < 2; dt++)
            #pragma unroll
            for (int c = 0; c < 2; c++){
                const short* a = &Vp[(dt * 32 + l32) * 68 + kq * 32 + c * 16 + hi * 8];
                vf[dt][c] = __builtin_shufflevector(*(const s16x4*)a, *(const s16x4*)(a + 4),
                                                    0,1,2,3,4,5,6,7);
            }
        #pragma unroll
        for (int qt = 0; qt < 2; qt++)
            #pragma unroll
            for (int dt = 0; dt < 2; dt++)
                #pragma unroll
                for (int c = 0; c < 2; c++)
                    oacc[qt][dt] = MFMA32(pf[qt][c], vf[dt][c], oacc[qt][dt]);
    }

    __syncthreads();   // everyone done with K/V buffers

    float* LO   = (float*)smem;            // [128][65] f32 (overlays K/V bufs)
    float* Lsum = (float*)&smem[17408];    // 128 f32
    float* Linv = (float*)&smem[17664];    // 128 f32

    float l0[2];
    #pragma unroll
    for (int qt = 0; qt < 2; qt++)
        l0[qt] = lacc[qt] + __shfl_xor(lacc[qt], 32);

    if (kq == 1){
        #pragma unroll
        for (int qt = 0; qt < 2; qt++)
            Lsum[wq * 64 + qt * 32 + l32] = l0[qt];
        #pragma unroll
        for (int qt = 0; qt < 2; qt++)
            #pragma unroll
            for (int dt = 0; dt < 2; dt++)
                #pragma unroll
                for (int e = 0; e < 16; e++){
                    int qrow = wq * 64 + qt * 32 + (e & 3) + 8 * (e >> 2) + 4 * hi;
                    LO[qrow * 65 + dt * 32 + l32] = oacc[qt][dt][e];
                }
    }
    __syncthreads();
    if (kq == 0){
        #pragma unroll
        for (int qt = 0; qt < 2; qt++){
            float lt = l0[qt] + Lsum[wq * 64 + qt * 32 + l32];
            Linv[wq * 64 + qt * 32 + l32] = 1.0f / lt;
        }
        asm volatile("s_waitcnt lgkmcnt(0)" ::: "memory");
        #pragma unroll
        for (int qt = 0; qt < 2; qt++)
            #pragma unroll
            for (int dt = 0; dt < 2; dt++)
                #pragma unroll
                for (int e = 0; e < 16; e++){
                    int qrow = wq * 64 + qt * 32 + (e & 3) + 8 * (e >> 2) + 4 * hi;
                    float val = (oacc[qt][dt][e] + LO[qrow * 65 + dt * 32 + l32]) * Linv[qrow];
                    o[((size_t)(b * N_ + n0 + qrow)) * C_ + h * D_ + dt * 32 + l32] = f2b(val);
                }
    }
}

extern "C" void kernel_launch(void* const* d_in, const int* in_sizes, int n_in,
                              void* d_out, int out_size, void* d_ws, size_t ws_size,
                              hipStream_t stream) {
    const float* query = (const float*)d_in[0];
    const float* key   = (const float*)d_in[1];
    const int*   qpos  = (const int*)d_in[2];
    const int*   kpos  = (const int*)d_in[3];
    const float* Wq    = (const float*)d_in[4];
    const float* bq    = (const float*)d_in[5];
    const float* Wk    = (const float*)d_in[6];
    const float* Wv    = (const float*)d_in[7];
    const float* bv    = (const float*)d_in[8];
    const float* Wo    = (const float*)d_in[9];
    const float* bo    = (const float*)d_in[10];
    float* out = (float*)d_out;

    const size_t E4M = (size_t)4 * 1024 * 1024;
    const size_t E1M = (size_t)1024 * 1024;
    short* ws    = (short*)d_ws;
    short* qbf   = ws;                    // 4M (dead after proj -> reused as attn)
    short* kbf   = qbf   + E4M;           // 4M
    short* wqkvb = kbf   + E4M;           // 3M = [Wq;Wk;Wv]
    short* wob   = wqkvb + 3 * E1M;       // 1M
    short* qproj = wob   + E1M;           // 4M
    short* kproj = qproj + E4M;           // 4M
    short* vT    = kproj + E4M;           // 4M  -> total 24M shorts = 48 MB
    short* attn  = qbf;                   // alias

    // 1) fused converts (12M elements, contiguous dst)
    cvt_all<<<6144, 256, 0, stream>>>(query, key, Wq, Wk, Wv, Wo, ws);

    // 2) fused QKV projection; V stored transposed in epilogue
    gemm_qkv<<<dim3(24, 32), 256, 0, stream>>>(qbf, kbf, wqkvb, bq, bv,
                                               qproj, kproj, vT);

    // 3) RoPE on k only (q-RoPE fused into flash prologue)
    rope_k<<<(B_ * M_ * H_ * 32) / 256, 256, 0, stream>>>(kproj, kpos);

    // 4) flash attention -> attn [B,N,C] bf16
    flash_attn<<<dim3(16, 32), 256, 0, stream>>>(qproj, kproj, vT, attn, qpos);

    // 5) output projection + bias + residual -> f32 out
    gemm_out<<<dim3(16, 32), 256, 0, stream>>>(attn, wob, bo, query, out);
}